// Round 16
// baseline (195.681 us; speedup 1.0000x reference)
//
#include <hip/hip_runtime.h>
#include <stdint.h>

typedef unsigned short u16;
typedef __bf16 bf16x8 __attribute__((ext_vector_type(8)));
typedef float f32x4 __attribute__((ext_vector_type(4)));
typedef float f32x16 __attribute__((ext_vector_type(16)));

#define NHEADS 16
#define DKH    128
#define SEQ    2048
#define DMODEL 2048
#define NBATCH 2

typedef const __attribute__((address_space(1))) void* gas1_t;
typedef __attribute__((address_space(3))) void* las3_t;

__device__ __forceinline__ void gload_lds16(const void* g, void* l) {
  __builtin_amdgcn_global_load_lds((gas1_t)(uintptr_t)g,
                                   (las3_t)(uint32_t)(uintptr_t)l, 16, 0, 0);
}

__device__ __forceinline__ u16 bf(float f) {
  return __builtin_bit_cast(u16, (__bf16)f);   // RNE convert
}

__device__ __forceinline__ uint32_t pk(float lo, float hi) {
  return (uint32_t)bf(lo) | ((uint32_t)bf(hi) << 16);
}

__device__ __forceinline__ float lanebcast(int srclane, float v) {
  return __builtin_bit_cast(float,
      __builtin_amdgcn_ds_bpermute(srclane << 2, __builtin_bit_cast(int, v)));
}

// ------- fused fp32 -> bf16 convert (x + wq|wk|wv) + RoPE table -------------
__global__ __launch_bounds__(256) void cvt_all(const float* __restrict__ x,
                                               const float* __restrict__ wq,
                                               const float* __restrict__ wk,
                                               const float* __restrict__ wv,
                                               u16* __restrict__ xb,
                                               u16* __restrict__ wb,
                                               float2* __restrict__ rope) {
  const int gb = blockIdx.x;
  if (gb >= 20480) {
    int i = (gb - 20480) * 256 + threadIdx.x;  // 2048*64 entries
    int s = i >> 6, d2 = i & 63;
    const float kLog2Theta = 13.28771237954945f;  // log2(10000)
    float inv_freq = exp2f(-(float)d2 * (2.0f / 128.0f) * kLog2Theta);
    float ang = (float)s * inv_freq;
    rope[i] = make_float2(cosf(ang), sinf(ang));
    return;
  }
  int i = (gb * 256 + threadIdx.x) * 4;
  const int NX = NBATCH * SEQ * DMODEL;  // 8388608
  const int NW = DMODEL * DMODEL;        // 4194304
  const float* src;
  u16* dst;
  int j;
  if (i < NX) { src = x; dst = xb; j = i; }
  else {
    int k = i - NX;
    int w = k / NW;
    j = k - w * NW;
    src = (w == 0) ? wq : (w == 1) ? wk : wv;
    dst = wb + (size_t)w * NW;
  }
  const float4 v = *(const float4*)(src + j);
  uint2 o;
  o.x = (uint32_t)bf(v.x) | ((uint32_t)bf(v.y) << 16);
  o.y = (uint32_t)bf(v.z) | ((uint32_t)bf(v.w) << 16);
  *(uint2*)(dst + j) = o;
}

// -------- fused QKV GEMM: [4096]x[6144] = xb @ wqkv^T, BK=64, swizzled -----
// (round-6 proven version: 128^2 tile, 256 thr, 4 blocks/CU, ~110 us / 43%)
__global__ __launch_bounds__(256, 4) void gemm_qkv(const u16* __restrict__ Abf,
                                                   const u16* __restrict__ Wbf,
                                                   const float2* __restrict__ rope,
                                                   u16* __restrict__ qb,
                                                   u16* __restrict__ kb,
                                                   u16* __restrict__ vtb) {
  __shared__ u16 S[16384];          // 32 KB: As | Bs, reused for V transpose
  u16* As = S;
  u16* Bs = S + 8192;
  const int tid = threadIdx.x;
  const int lane = tid & 63, wid = tid >> 6;
  const int wr = wid >> 1, wc = wid & 1;
  const int blk = blockIdx.x;                 // 1536 blocks
  const int m0 = (blk / 48) * 128;            // m-tile (32), slow
  const int n0 = (blk % 48) * 128;            // n-tile (48), fast
  const int lrow = lane & 15, lgrp = lane >> 4, lko = lgrp * 8;
  const int rswz = (lrow & 7) << 3;

  const int srow = tid >> 3;
  const int scol = ((tid & 7) * 8) ^ (((tid >> 3) & 7) << 3);

  f32x4 acc[4][4] = {};

  for (int k0 = 0; k0 < DMODEL; k0 += 64) {
    __syncthreads();
#pragma unroll
    for (int c = 0; c < 4; ++c) {
      gload_lds16(Abf + (size_t)(m0 + c * 32 + srow) * DMODEL + k0 + scol,
                  As + (c * 256 + tid) * 8);
      gload_lds16(Wbf + (size_t)(n0 + c * 32 + srow) * DMODEL + k0 + scol,
                  Bs + (c * 256 + tid) * 8);
    }
    __syncthreads();
#pragma unroll
    for (int kk = 0; kk < 2; ++kk) {
      const int rc = (kk * 32 + lko) ^ rswz;
      bf16x8 a[4], b[4];
#pragma unroll
      for (int m = 0; m < 4; ++m)
        a[m] = *(const bf16x8*)(As + (wr * 64 + m * 16 + lrow) * 64 + rc);
#pragma unroll
      for (int n = 0; n < 4; ++n)
        b[n] = *(const bf16x8*)(Bs + (wc * 64 + n * 16 + lrow) * 64 + rc);
#pragma unroll
      for (int m = 0; m < 4; ++m)
#pragma unroll
        for (int n = 0; n < 4; ++n)
          acc[m][n] = __builtin_amdgcn_mfma_f32_16x16x32_bf16(a[m], b[n], acc[m][n], 0, 0, 0);
    }
  }

  const int sel = n0 >> 11;  // 0=Q, 1=K, 2=V (block-uniform)
  const float qsc = 0.08838834764831845f * 1.44269504088896341f;

  if (sel != 2) {
#pragma unroll
    for (int m = 0; m < 4; ++m) {
      int grow0 = m0 + wr * 64 + m * 16 + (lgrp << 2);
#pragma unroll
      for (int n = 0; n < 4; ++n) {
        int gcol = n0 + wc * 64 + n * 16 + lrow;
        int within = gcol & 2047;
        int h_ = within >> 7, d_ = within & 127;
#pragma unroll
        for (int j = 0; j < 4; ++j) {
          float v = acc[m][n][j];
          int r = grow0 + j;
          int b_ = r >> 11, s_ = r & 2047;
          int bh = b_ * NHEADS + h_;
          float part = __shfl_xor(v, 1);
          float2 cs2 = rope[s_ * 64 + (d_ >> 1)];
          v = (d_ & 1) ? (part * cs2.y + v * cs2.x) : (v * cs2.x - part * cs2.y);
          if (sel == 0) v *= qsc;
          u16* dq = sel ? kb : qb;
          dq[((size_t)bh * SEQ + s_) * DKH + d_] = bf(v);
        }
      }
    }
  } else {
    // V: transpose through LDS, coalesced Vt row writes
    __syncthreads();
#pragma unroll
    for (int m = 0; m < 4; ++m) {
      int sl0 = wr * 64 + m * 16 + (lgrp << 2);
#pragma unroll
      for (int n = 0; n < 4; ++n) {
        int dcol = wc * 64 + n * 16 + lrow;
        const int dx = (dcol & 7) << 4;
#pragma unroll
        for (int j = 0; j < 4; ++j)
          S[dcol * 128 + ((sl0 + j) ^ dx)] = bf(acc[m][n][j]);
      }
    }
    __syncthreads();
    const int b_ = m0 >> 11, s0 = m0 & 2047;
    const int h_ = (n0 >> 7) & 15;
    const int bh = b_ * NHEADS + h_;
    const int d = tid >> 1, hf = tid & 1;
    const int dx = (d & 7) << 4;
    u16* grow = vtb + ((size_t)bh * DKH + d) * SEQ + s0 + hf * 64;
#pragma unroll
    for (int g = 0; g < 8; ++g) {
      bf16x8 v8 = *(const bf16x8*)(S + d * 128 + ((hf * 64 + g * 8) ^ dx));
      *(bf16x8*)(grow + g * 8) = v8;
    }
  }
}

// ---------------- causal flash attention: 32x32 MFMA, swapped QK^T ---------
// r12 schedule + T4 counted-vmcnt: K TRIPLE-buffered (K(t+2) issued each
// iter, lands 2 iterations later), V double-buffered (V(t+1) 1 ahead).
// Issue order per iter: V(t+1) first, then K(t+2); end-of-tile waits
// s_waitcnt vmcnt(4) -- drains the oldest 8 (K(t+1), V(t+1)), leaves
// K(t+2)'s 4 loads in flight across the raw s_barrier (the asm "memory"
// clobber provides the compiler fence; proven pattern from r10/r11).
// Tail (t+2 >= nt): vmcnt(0), wave-uniform. LDS 48+32 = 80 KB -> 2 blocks/CU
// = 160 KiB exactly. 512 blocks; b and b+256 carry complementary chunks
// (p, 15-p) of the SAME bh; XCD-affine bh&7 == blk&7.
__global__ __launch_bounds__(256, 2) void attn_fwd(const u16* __restrict__ qb,
                                                   const u16* __restrict__ kb,
                                                   const u16* __restrict__ vtb,
                                                   float* __restrict__ out) {
  __shared__ u16 Ks[3][64 * 128];   // [kv 64][d 128], 16-slot swizzle, 48 KB
  __shared__ u16 Vs[2][128 * 64];   // [d 128][kv 64],  8-slot swizzle, 32 KB
  const int tid = threadIdx.x, lane = tid & 63, wid = tid >> 6;
  const int blk = blockIdx.x;       // 512 blocks
  const int r_ = blk & 255, half = blk >> 8;
  const int bh = r_ & 31;           // xcd = bh&7 = blk&7
  const int pairidx = r_ >> 5;      // 0..7
  const int chunk = half ? (15 - pairidx) : pairidx;
  const int qln = lane & 31, hi = lane >> 5;
  const int hi4 = hi << 2, hi8 = hi << 3;
  const int kswz = (qln & 15) << 3;
  const int vswz = (qln & 7) << 3;

  const int krow_l = tid >> 4;                       // 0..15
  const int kcol = (((tid & 15) ^ (tid >> 4)) << 3); // 16-slot src swizzle
  const int vrow_l = tid >> 3;                       // 0..31
  const int vcol = (((tid & 7) ^ ((tid >> 3) & 7)) << 3);

  const int b_ = bh >> 4, h_ = bh & 15;
  const size_t kbase = (size_t)bh * SEQ;
  const size_t vbase = (size_t)bh * DKH;

#define STAGE_K(bufi, kv_)                                                   \
  _Pragma("unroll")                                                          \
  for (int c = 0; c < 4; ++c)                                                \
    gload_lds16(kb + (kbase + (kv_) + c * 16 + krow_l) * DKH + kcol,         \
                &Ks[bufi][(c * 256 + tid) * 8]);
#define STAGE_V(bufi, kv_)                                                   \
  _Pragma("unroll")                                                          \
  for (int c = 0; c < 4; ++c)                                                \
    gload_lds16(vtb + (vbase + c * 32 + vrow_l) * SEQ + (kv_) + vcol,        \
                &Vs[bufi][(c * 256 + tid) * 8]);

  const int q0w = chunk * 128 + wid * 32;
  const int qglob = q0w + qln;

  bf16x8 qa[8];
#pragma unroll
  for (int kd = 0; kd < 8; ++kd)
    qa[kd] = *(const bf16x8*)(qb + (kbase + q0w + qln) * DKH + kd * 16 + hi8);

  f32x16 o[4] = {};
  float mrun = -1e30f, lrun = 0.f;

  const int nt = 2 * chunk + 2;  // >= 2 always

  // prologue: K(0), V(0) (oldest 8), then K(1) in flight
  STAGE_K(0, 0);
  STAGE_V(0, 0);
  STAGE_K(1, 64);
  asm volatile("s_waitcnt vmcnt(4)" ::: "memory");  // K0,V0 landed; K1 flies
  __builtin_amdgcn_s_barrier();

  int kcur = 0;  // K buffer of tile t (rotates mod 3)

#pragma unroll 1
  for (int t = 0; t < nt; ++t) {
    const int kv0 = t * 64;
    const bool pf2 = (t + 2 < nt);

    // issue V(t+1) FIRST (must drain this iter), then K(t+2) (2-deep)
    if (t + 1 < nt) { STAGE_V((t + 1) & 1, (t + 1) * 64); }
    if (pf2) {
      int kw = kcur + 2; if (kw >= 3) kw -= 3;
      STAGE_K(kw, (t + 2) * 64);
    }

    if (kv0 <= q0w + 31) {  // wave-uniform: skip fully-masked tile
      const u16* Kb = &Ks[kcur][0];
      const u16* Vb = &Vs[t & 1][0];

      // S^T = K . Q^T : lane holds column q = qln, 16 kv-rows per subtile
      f32x16 sfv[2] = {};
      __builtin_amdgcn_s_setprio(1);
#pragma unroll
      for (int kd = 0; kd < 8; ++kd)
#pragma unroll
        for (int st = 0; st < 2; ++st) {
          bf16x8 kf = *(const bf16x8*)(Kb + (st * 32 + qln) * 128 +
                                       ((kd * 16 + hi8) ^ kswz));
          sfv[st] = __builtin_amdgcn_mfma_f32_32x32x16_bf16(kf, qa[kd], sfv[st], 0, 0, 0);
        }
      __builtin_amdgcn_s_setprio(0);

      // causal mask (only the wave's diagonal tile)
      if (kv0 + 63 > q0w) {
#pragma unroll
        for (int st = 0; st < 2; ++st)
#pragma unroll
          for (int r = 0; r < 16; ++r)
            if (kv0 + st * 32 + ((r & 3) + 8 * (r >> 2)) + hi4 > qglob)
              sfv[st][r] = -1e30f;
      }

      // row max
      float tm[16];
#pragma unroll
      for (int r = 0; r < 16; ++r) tm[r] = fmaxf(sfv[0][r], sfv[1][r]);
#pragma unroll
      for (int r = 0; r < 8; ++r) tm[r] = fmaxf(tm[r], tm[r + 8]);
#pragma unroll
      for (int r = 0; r < 4; ++r) tm[r] = fmaxf(tm[r], tm[r + 4]);
      float m_ = fmaxf(fmaxf(tm[0], tm[1]), fmaxf(tm[2], tm[3]));
      m_ = fmaxf(m_, __shfl_xor(m_, 32));

      // deferred rescale (exp2 domain, THR = 11.5)
      if (__any(m_ > mrun + 11.5f)) {
        float mnew = fmaxf(mrun, m_);
        float alpha = __builtin_amdgcn_exp2f(mrun - mnew);
        mrun = mnew;
        lrun *= alpha;
#pragma unroll
        for (int r = 0; r < 16; ++r) {
          float ar = lanebcast((r & 3) + 8 * (r >> 2) + hi4, alpha);
          o[0][r] *= ar; o[1][r] *= ar; o[2][r] *= ar; o[3][r] *= ar;
        }
      }

      // P = exp2(S - m), row sum
#pragma unroll
      for (int st = 0; st < 2; ++st)
#pragma unroll
        for (int r = 0; r < 16; ++r)
          sfv[st][r] = __builtin_amdgcn_exp2f(sfv[st][r] - mrun);
      float ts[16];
#pragma unroll
      for (int r = 0; r < 16; ++r) ts[r] = sfv[0][r] + sfv[1][r];
#pragma unroll
      for (int r = 0; r < 8; ++r) ts[r] += ts[r + 8];
#pragma unroll
      for (int r = 0; r < 4; ++r) ts[r] += ts[r + 4];
      float sum = (ts[0] + ts[1]) + (ts[2] + ts[3]);
      sum += __shfl_xor(sum, 32);
      lrun += sum;

      // PV: build A-frag in-register per 16-kv slice, O += P.V^T
      __builtin_amdgcn_s_setprio(1);
#pragma unroll
      for (int ks = 0; ks < 4; ++ks) {
        const int st = ks >> 1, rb = (ks & 1) * 8;
        uint32_t w0 = pk(sfv[st][rb + 0], sfv[st][rb + 1]);
        uint32_t w1 = pk(sfv[st][rb + 2], sfv[st][rb + 3]);
        uint32_t w2 = pk(sfv[st][rb + 4], sfv[st][rb + 5]);
        uint32_t w3 = pk(sfv[st][rb + 6], sfv[st][rb + 7]);
        uint32_t s0 = hi ? w0 : w2, s1 = hi ? w1 : w3;
        uint32_t r0 = (uint32_t)__shfl_xor((int)s0, 32);
        uint32_t r1 = (uint32_t)__shfl_xor((int)s1, 32);
        union { uint32_t u[4]; bf16x8 v; } pa;
        pa.u[0] = hi ? r0 : w0;
        pa.u[1] = hi ? r1 : w1;
        pa.u[2] = hi ? w2 : r0;
        pa.u[3] = hi ? w3 : r1;
#pragma unroll
        for (int d0 = 0; d0 < 4; ++d0) {
          bf16x8 vf = *(const bf16x8*)(Vb + (d0 * 32 + qln) * 64 +
                                       ((ks * 16 + hi8) ^ vswz));
          o[d0] = __builtin_amdgcn_mfma_f32_32x32x16_bf16(pa.v, vf, o[d0], 0, 0, 0);
        }
      }
      __builtin_amdgcn_s_setprio(0);
    }

    // counted drain: K(t+1)+V(t+1) land (oldest 8), K(t+2) stays in flight
    if (pf2) asm volatile("s_waitcnt vmcnt(4)" ::: "memory");
    else     asm volatile("s_waitcnt vmcnt(0)" ::: "memory");
    __builtin_amdgcn_s_barrier();

    ++kcur; if (kcur == 3) kcur = 0;
  }

  // epilogue
  float inv = 1.f / lrun;
#pragma unroll
  for (int r = 0; r < 16; ++r) {
    const int qr = (r & 3) + 8 * (r >> 2) + hi4;
    float invr = lanebcast(qr, inv);
    float* op = out + ((size_t)b_ * SEQ + q0w + qr) * DMODEL + h_ * DKH + qln;
    op[0]  = o[0][r] * invr;
    op[32] = o[1][r] * invr;
    op[64] = o[2][r] * invr;
    op[96] = o[3][r] * invr;
  }
#undef STAGE_K
#undef STAGE_V
}

extern "C" void kernel_launch(void* const* d_in, const int* in_sizes, int n_in,
                              void* d_out, int out_size, void* d_ws, size_t ws_size,
                              hipStream_t stream) {
  const float* x  = (const float*)d_in[0];
  const float* wq = (const float*)d_in[1];
  const float* wk = (const float*)d_in[2];
  const float* wv = (const float*)d_in[3];
  float* out = (float*)d_out;
  char* ws = (char*)d_ws;

  u16* xb  = (u16*)(ws);                       // 16 MB
  u16* wb  = (u16*)(ws + 16777216);            // 24 MB  wq|wk|wv bf16 [6144][2048]
  u16* qb  = (u16*)(ws + 41943040);            // 16 MB  [bh][s][d] (pre-scaled)
  u16* kb  = (u16*)(ws + 58720256);            // 16 MB  [bh][s][d]
  u16* vtb = (u16*)(ws + 75497472);            // 16 MB  [bh][d][s]

  // RoPE table in the first 1 MB of d_out (consumed before attn overwrites).
  float2* rope = (float2*)d_out;               // 2048*64*8 = 1 MB

  cvt_all<<<20992, 256, 0, stream>>>(x, wq, wk, wv, xb, wb, rope);
  gemm_qkv<<<1536, 256, 0, stream>>>(xb, wb, rope, qb, kb, vtb);
  attn_fwd<<<512, 256, 0, stream>>>(qb, kb, vtb, out);
}

// Round 17
// 187.246 us; speedup vs baseline: 1.0450x; 1.0450x over previous
//
#include <hip/hip_runtime.h>
#include <stdint.h>

typedef unsigned short u16;
typedef __bf16 bf16x8 __attribute__((ext_vector_type(8)));
typedef float f32x4 __attribute__((ext_vector_type(4)));
typedef float f32x16 __attribute__((ext_vector_type(16)));

#define NHEADS 16
#define DKH    128
#define SEQ    2048
#define DMODEL 2048
#define NBATCH 2

typedef const __attribute__((address_space(1))) void* gas1_t;
typedef __attribute__((address_space(3))) void* las3_t;

__device__ __forceinline__ void gload_lds16(const void* g, void* l) {
  __builtin_amdgcn_global_load_lds((gas1_t)(uintptr_t)g,
                                   (las3_t)(uint32_t)(uintptr_t)l, 16, 0, 0);
}

__device__ __forceinline__ u16 bf(float f) {
  return __builtin_bit_cast(u16, (__bf16)f);   // RNE convert
}

__device__ __forceinline__ uint32_t pk(float lo, float hi) {
  return (uint32_t)bf(lo) | ((uint32_t)bf(hi) << 16);
}

__device__ __forceinline__ float lanebcast(int srclane, float v) {
  return __builtin_bit_cast(float,
      __builtin_amdgcn_ds_bpermute(srclane << 2, __builtin_bit_cast(int, v)));
}

// ------- fused fp32 -> bf16 convert (x + wq|wk|wv) + RoPE table -------------
__global__ __launch_bounds__(256) void cvt_all(const float* __restrict__ x,
                                               const float* __restrict__ wq,
                                               const float* __restrict__ wk,
                                               const float* __restrict__ wv,
                                               u16* __restrict__ xb,
                                               u16* __restrict__ wb,
                                               float2* __restrict__ rope) {
  const int gb = blockIdx.x;
  if (gb >= 20480) {
    int i = (gb - 20480) * 256 + threadIdx.x;  // 2048*64 entries
    int s = i >> 6, d2 = i & 63;
    const float kLog2Theta = 13.28771237954945f;  // log2(10000)
    float inv_freq = exp2f(-(float)d2 * (2.0f / 128.0f) * kLog2Theta);
    float ang = (float)s * inv_freq;
    rope[i] = make_float2(cosf(ang), sinf(ang));
    return;
  }
  int i = (gb * 256 + threadIdx.x) * 4;
  const int NX = NBATCH * SEQ * DMODEL;  // 8388608
  const int NW = DMODEL * DMODEL;        // 4194304
  const float* src;
  u16* dst;
  int j;
  if (i < NX) { src = x; dst = xb; j = i; }
  else {
    int k = i - NX;
    int w = k / NW;
    j = k - w * NW;
    src = (w == 0) ? wq : (w == 1) ? wk : wv;
    dst = wb + (size_t)w * NW;
  }
  const float4 v = *(const float4*)(src + j);
  uint2 o;
  o.x = (uint32_t)bf(v.x) | ((uint32_t)bf(v.y) << 16);
  o.y = (uint32_t)bf(v.z) | ((uint32_t)bf(v.w) << 16);
  *(uint2*)(dst + j) = o;
}

// -------- fused QKV GEMM: [4096]x[6144] = xb @ wqkv^T, BK=64, swizzled -----
// (round-6 proven version: 128^2 tile, 256 thr, 4 blocks/CU, ~110 us / 43%)
__global__ __launch_bounds__(256, 4) void gemm_qkv(const u16* __restrict__ Abf,
                                                   const u16* __restrict__ Wbf,
                                                   const float2* __restrict__ rope,
                                                   u16* __restrict__ qb,
                                                   u16* __restrict__ kb,
                                                   u16* __restrict__ vtb) {
  __shared__ u16 S[16384];          // 32 KB: As | Bs, reused for V transpose
  u16* As = S;
  u16* Bs = S + 8192;
  const int tid = threadIdx.x;
  const int lane = tid & 63, wid = tid >> 6;
  const int wr = wid >> 1, wc = wid & 1;
  const int blk = blockIdx.x;                 // 1536 blocks
  const int m0 = (blk / 48) * 128;            // m-tile (32), slow
  const int n0 = (blk % 48) * 128;            // n-tile (48), fast
  const int lrow = lane & 15, lgrp = lane >> 4, lko = lgrp * 8;
  const int rswz = (lrow & 7) << 3;

  const int srow = tid >> 3;
  const int scol = ((tid & 7) * 8) ^ (((tid >> 3) & 7) << 3);

  f32x4 acc[4][4] = {};

  for (int k0 = 0; k0 < DMODEL; k0 += 64) {
    __syncthreads();
#pragma unroll
    for (int c = 0; c < 4; ++c) {
      gload_lds16(Abf + (size_t)(m0 + c * 32 + srow) * DMODEL + k0 + scol,
                  As + (c * 256 + tid) * 8);
      gload_lds16(Wbf + (size_t)(n0 + c * 32 + srow) * DMODEL + k0 + scol,
                  Bs + (c * 256 + tid) * 8);
    }
    __syncthreads();
#pragma unroll
    for (int kk = 0; kk < 2; ++kk) {
      const int rc = (kk * 32 + lko) ^ rswz;
      bf16x8 a[4], b[4];
#pragma unroll
      for (int m = 0; m < 4; ++m)
        a[m] = *(const bf16x8*)(As + (wr * 64 + m * 16 + lrow) * 64 + rc);
#pragma unroll
      for (int n = 0; n < 4; ++n)
        b[n] = *(const bf16x8*)(Bs + (wc * 64 + n * 16 + lrow) * 64 + rc);
#pragma unroll
      for (int m = 0; m < 4; ++m)
#pragma unroll
        for (int n = 0; n < 4; ++n)
          acc[m][n] = __builtin_amdgcn_mfma_f32_16x16x32_bf16(a[m], b[n], acc[m][n], 0, 0, 0);
    }
  }

  const int sel = n0 >> 11;  // 0=Q, 1=K, 2=V (block-uniform)
  const float qsc = 0.08838834764831845f * 1.44269504088896341f;

  if (sel != 2) {
#pragma unroll
    for (int m = 0; m < 4; ++m) {
      int grow0 = m0 + wr * 64 + m * 16 + (lgrp << 2);
#pragma unroll
      for (int n = 0; n < 4; ++n) {
        int gcol = n0 + wc * 64 + n * 16 + lrow;
        int within = gcol & 2047;
        int h_ = within >> 7, d_ = within & 127;
#pragma unroll
        for (int j = 0; j < 4; ++j) {
          float v = acc[m][n][j];
          int r = grow0 + j;
          int b_ = r >> 11, s_ = r & 2047;
          int bh = b_ * NHEADS + h_;
          float part = __shfl_xor(v, 1);
          float2 cs2 = rope[s_ * 64 + (d_ >> 1)];
          v = (d_ & 1) ? (part * cs2.y + v * cs2.x) : (v * cs2.x - part * cs2.y);
          if (sel == 0) v *= qsc;
          u16* dq = sel ? kb : qb;
          dq[((size_t)bh * SEQ + s_) * DKH + d_] = bf(v);
        }
      }
    }
  } else {
    // V: transpose through LDS, coalesced Vt row writes
    __syncthreads();
#pragma unroll
    for (int m = 0; m < 4; ++m) {
      int sl0 = wr * 64 + m * 16 + (lgrp << 2);
#pragma unroll
      for (int n = 0; n < 4; ++n) {
        int dcol = wc * 64 + n * 16 + lrow;
        const int dx = (dcol & 7) << 4;
#pragma unroll
        for (int j = 0; j < 4; ++j)
          S[dcol * 128 + ((sl0 + j) ^ dx)] = bf(acc[m][n][j]);
      }
    }
    __syncthreads();
    const int b_ = m0 >> 11, s0 = m0 & 2047;
    const int h_ = (n0 >> 7) & 15;
    const int bh = b_ * NHEADS + h_;
    const int d = tid >> 1, hf = tid & 1;
    const int dx = (d & 7) << 4;
    u16* grow = vtb + ((size_t)bh * DKH + d) * SEQ + s0 + hf * 64;
#pragma unroll
    for (int g = 0; g < 8; ++g) {
      bf16x8 v8 = *(const bf16x8*)(S + d * 128 + ((hf * 64 + g * 8) ^ dx));
      *(bf16x8*)(grow + g * 8) = v8;
    }
  }
}

// ---------------- causal flash attention: 32x32 MFMA, swapped QK^T ---------
// (round-12 proven version: K and V both double-buffered, stage(t+1) issued
// before compute(t), ONE barrier per tile. 64 KB LDS, 2 blocks/CU. 512
// blocks; blocks b and b+256 carry complementary chunks (p, 15-p) of the
// SAME bh; XCD-affine bh&7 == blk&7. Lessons: r13 direct-global K/V reads
// latency-unhidden (164 us); r14 mid-tile barrier convoys (88 us); r16
// triple-K counted-vmcnt adds critical-path work (66 us). This: ~58 us.)
__global__ __launch_bounds__(256, 2) void attn_fwd(const u16* __restrict__ qb,
                                                   const u16* __restrict__ kb,
                                                   const u16* __restrict__ vtb,
                                                   float* __restrict__ out) {
  __shared__ u16 Ks[2][64 * 128];   // [kv 64][d 128], 16-slot swizzle
  __shared__ u16 Vs[2][128 * 64];   // [d 128][kv 64],  8-slot swizzle
  const int tid = threadIdx.x, lane = tid & 63, wid = tid >> 6;
  const int blk = blockIdx.x;       // 512 blocks
  const int r_ = blk & 255, half = blk >> 8;
  const int bh = r_ & 31;           // xcd = bh&7 = blk&7
  const int pairidx = r_ >> 5;      // 0..7
  const int chunk = half ? (15 - pairidx) : pairidx;
  const int qln = lane & 31, hi = lane >> 5;
  const int hi4 = hi << 2, hi8 = hi << 3;
  const int kswz = (qln & 15) << 3;
  const int vswz = (qln & 7) << 3;

  const int krow_l = tid >> 4;                       // 0..15
  const int kcol = (((tid & 15) ^ (tid >> 4)) << 3); // 16-slot src swizzle
  const int vrow_l = tid >> 3;                       // 0..31
  const int vcol = (((tid & 7) ^ ((tid >> 3) & 7)) << 3);

  const int b_ = bh >> 4, h_ = bh & 15;
  const size_t kbase = (size_t)bh * SEQ;
  const size_t vbase = (size_t)bh * DKH;

#define STAGE_KV(bufi, kv_)                                                  \
  _Pragma("unroll")                                                          \
  for (int c = 0; c < 4; ++c) {                                              \
    gload_lds16(kb + (kbase + (kv_) + c * 16 + krow_l) * DKH + kcol,         \
                &Ks[bufi][(c * 256 + tid) * 8]);                             \
    gload_lds16(vtb + (vbase + c * 32 + vrow_l) * SEQ + (kv_) + vcol,        \
                &Vs[bufi][(c * 256 + tid) * 8]);                             \
  }

  const int q0w = chunk * 128 + wid * 32;
  const int qglob = q0w + qln;

  bf16x8 qa[8];
#pragma unroll
  for (int kd = 0; kd < 8; ++kd)
    qa[kd] = *(const bf16x8*)(qb + (kbase + q0w + qln) * DKH + kd * 16 + hi8);

  f32x16 o[4] = {};
  float mrun = -1e30f, lrun = 0.f;

  const int nt = 2 * chunk + 2;

  STAGE_KV(0, 0);
  __syncthreads();

#pragma unroll 1
  for (int t = 0; t < nt; ++t) {
    const int cur = t & 1;
    if (t + 1 < nt) { STAGE_KV(cur ^ 1, (t + 1) * 64); }
    const int kv0 = t * 64;

    if (kv0 <= q0w + 31) {  // wave-uniform: skip fully-masked tile
      const u16* Kb = &Ks[cur][0];
      const u16* Vb = &Vs[cur][0];

      // S^T = K . Q^T : lane holds column q = qln, 16 kv-rows per subtile
      f32x16 sfv[2] = {};
      __builtin_amdgcn_s_setprio(1);
#pragma unroll
      for (int kd = 0; kd < 8; ++kd)
#pragma unroll
        for (int st = 0; st < 2; ++st) {
          bf16x8 kf = *(const bf16x8*)(Kb + (st * 32 + qln) * 128 +
                                       ((kd * 16 + hi8) ^ kswz));
          sfv[st] = __builtin_amdgcn_mfma_f32_32x32x16_bf16(kf, qa[kd], sfv[st], 0, 0, 0);
        }
      __builtin_amdgcn_s_setprio(0);

      // causal mask (only the wave's diagonal tile)
      if (kv0 + 63 > q0w) {
#pragma unroll
        for (int st = 0; st < 2; ++st)
#pragma unroll
          for (int r = 0; r < 16; ++r)
            if (kv0 + st * 32 + ((r & 3) + 8 * (r >> 2)) + hi4 > qglob)
              sfv[st][r] = -1e30f;
      }

      // row max
      float tm[16];
#pragma unroll
      for (int r = 0; r < 16; ++r) tm[r] = fmaxf(sfv[0][r], sfv[1][r]);
#pragma unroll
      for (int r = 0; r < 8; ++r) tm[r] = fmaxf(tm[r], tm[r + 8]);
#pragma unroll
      for (int r = 0; r < 4; ++r) tm[r] = fmaxf(tm[r], tm[r + 4]);
      float m_ = fmaxf(fmaxf(tm[0], tm[1]), fmaxf(tm[2], tm[3]));
      m_ = fmaxf(m_, __shfl_xor(m_, 32));

      // deferred rescale (exp2 domain, THR = 11.5)
      if (__any(m_ > mrun + 11.5f)) {
        float mnew = fmaxf(mrun, m_);
        float alpha = __builtin_amdgcn_exp2f(mrun - mnew);
        mrun = mnew;
        lrun *= alpha;
#pragma unroll
        for (int r = 0; r < 16; ++r) {
          float ar = lanebcast((r & 3) + 8 * (r >> 2) + hi4, alpha);
          o[0][r] *= ar; o[1][r] *= ar; o[2][r] *= ar; o[3][r] *= ar;
        }
      }

      // P = exp2(S - m), row sum
#pragma unroll
      for (int st = 0; st < 2; ++st)
#pragma unroll
        for (int r = 0; r < 16; ++r)
          sfv[st][r] = __builtin_amdgcn_exp2f(sfv[st][r] - mrun);
      float ts[16];
#pragma unroll
      for (int r = 0; r < 16; ++r) ts[r] = sfv[0][r] + sfv[1][r];
#pragma unroll
      for (int r = 0; r < 8; ++r) ts[r] += ts[r + 8];
#pragma unroll
      for (int r = 0; r < 4; ++r) ts[r] += ts[r + 4];
      float sum = (ts[0] + ts[1]) + (ts[2] + ts[3]);
      sum += __shfl_xor(sum, 32);
      lrun += sum;

      // PV: build A-frag in-register per 16-kv slice, O += P.V^T
      __builtin_amdgcn_s_setprio(1);
#pragma unroll
      for (int ks = 0; ks < 4; ++ks) {
        const int st = ks >> 1, rb = (ks & 1) * 8;
        uint32_t w0 = pk(sfv[st][rb + 0], sfv[st][rb + 1]);
        uint32_t w1 = pk(sfv[st][rb + 2], sfv[st][rb + 3]);
        uint32_t w2 = pk(sfv[st][rb + 4], sfv[st][rb + 5]);
        uint32_t w3 = pk(sfv[st][rb + 6], sfv[st][rb + 7]);
        uint32_t s0 = hi ? w0 : w2, s1 = hi ? w1 : w3;
        uint32_t r0 = (uint32_t)__shfl_xor((int)s0, 32);
        uint32_t r1 = (uint32_t)__shfl_xor((int)s1, 32);
        union { uint32_t u[4]; bf16x8 v; } pa;
        pa.u[0] = hi ? r0 : w0;
        pa.u[1] = hi ? r1 : w1;
        pa.u[2] = hi ? w2 : r0;
        pa.u[3] = hi ? w3 : r1;
#pragma unroll
        for (int d0 = 0; d0 < 4; ++d0) {
          bf16x8 vf = *(const bf16x8*)(Vb + (d0 * 32 + qln) * 64 +
                                       ((ks * 16 + hi8) ^ vswz));
          o[d0] = __builtin_amdgcn_mfma_f32_32x32x16_bf16(pa.v, vf, o[d0], 0, 0, 0);
        }
      }
      __builtin_amdgcn_s_setprio(0);
    }

    __syncthreads();  // staging drained (hidden under compute) + handoff
  }

  // epilogue
  float inv = 1.f / lrun;
#pragma unroll
  for (int r = 0; r < 16; ++r) {
    const int qr = (r & 3) + 8 * (r >> 2) + hi4;
    float invr = lanebcast(qr, inv);
    float* op = out + ((size_t)b_ * SEQ + q0w + qr) * DMODEL + h_ * DKH + qln;
    op[0]  = o[0][r] * invr;
    op[32] = o[1][r] * invr;
    op[64] = o[2][r] * invr;
    op[96] = o[3][r] * invr;
  }
#undef STAGE_KV
}

extern "C" void kernel_launch(void* const* d_in, const int* in_sizes, int n_in,
                              void* d_out, int out_size, void* d_ws, size_t ws_size,
                              hipStream_t stream) {
  const float* x  = (const float*)d_in[0];
  const float* wq = (const float*)d_in[1];
  const float* wk = (const float*)d_in[2];
  const float* wv = (const float*)d_in[3];
  float* out = (float*)d_out;
  char* ws = (char*)d_ws;

  u16* xb  = (u16*)(ws);                       // 16 MB
  u16* wb  = (u16*)(ws + 16777216);            // 24 MB  wq|wk|wv bf16 [6144][2048]
  u16* qb  = (u16*)(ws + 41943040);            // 16 MB  [bh][s][d] (pre-scaled)
  u16* kb  = (u16*)(ws + 58720256);            // 16 MB  [bh][s][d]
  u16* vtb = (u16*)(ws + 75497472);            // 16 MB  [bh][d][s]

  // RoPE table in the first 1 MB of d_out (consumed before attn overwrites).
  float2* rope = (float2*)d_out;               // 2048*64*8 = 1 MB

  cvt_all<<<20992, 256, 0, stream>>>(x, wq, wk, wv, xb, wb, rope);
  gemm_qkv<<<1536, 256, 0, stream>>>(xb, wb, rope, qb, kb, vtb);
  attn_fwd<<<512, 256, 0, stream>>>(qb, kb, vtb, out);
}